// Round 5
// baseline (2857.627 us; speedup 1.0000x reference)
//
#include <hip/hip_runtime.h>
#include <math.h>

namespace {

constexpr int Bb = 4, Ss = 1024, Dd = 1024, Hh = 16, HDim = 64, Nn = 4096;
constexpr int Mm = Bb * Ss; // 4096

// ---------------------------------------------------------------------------
// fp32 GEMM v3: C[M,N] = A[M,K] @ W[N,K]^T (+ bias[N]).
// Block = 128 threads (2 waves). Tile BM x 128, BM = TM*8, BK=16.
// Per thread TM x 8 outputs -> (TM+8)*4 bytes LDS per TM*8 FMA:
//   TM=16 -> 0.75 B/FMA (LDS no longer co-limiting; FMA-bound)
//   TM=8  -> 1.0  B/FMA (used for the small ctx GEMM to keep grid >= 512)
// Single LDS buffer, 2 barriers/tile; global prefetch for tile kt+1 issued
// AFTER the stores-visible barrier so its vmcnt wait lands after the full
// compute phase (fixes r4's exposed-latency-at-barrier bug).
// MODE 0: C = acc + bias.  MODE 2 (TM=16 only): partial[blockIdx.y][n] =
// max over the tile's 128 rows (feeds router pooled max).
// ---------------------------------------------------------------------------
template <int MODE, int TM>
__global__ __launch_bounds__(128, 2) void gemm_f32(
    const float* __restrict__ A, const float* __restrict__ W,
    const float* __restrict__ bias, float* __restrict__ C, const int K,
    const int ldc) {
  constexpr int BM = TM * 8;
  __shared__ float As[16][BM];
  __shared__ float Ws[16][128];
  __shared__ float red[2][128];  // MODE2 cross-wave reduction
  const int tid = threadIdx.x;
  const int rg = tid >> 4, cg = tid & 15;  // output row-group / col-group
  const int m0 = blockIdx.y * BM, n0 = blockIdx.x * 128;

  // staging mapping
  const int brow = tid;  // B: thread loads full row (16 floats)
  int arow, ahalf;
  if constexpr (TM == 16) { arow = tid; ahalf = 0; }
  else { arow = tid >> 1; ahalf = (tid & 1) * 8; }
  const float* Ap = A + (size_t)(m0 + arow) * K + ahalf;
  const float* Wp = W + (size_t)(n0 + brow) * K;

  float4 ar[4], br[4];
  if constexpr (TM == 16) {
#pragma unroll
    for (int c = 0; c < 4; ++c) ar[c] = *(const float4*)(Ap + 4 * c);
  } else {
    ar[0] = *(const float4*)(Ap);
    ar[1] = *(const float4*)(Ap + 4);
  }
#pragma unroll
  for (int c = 0; c < 4; ++c) br[c] = *(const float4*)(Wp + 4 * c);

  float acc[TM][8] = {};
  const int NT = K / 16;
#pragma unroll 1
  for (int kt = 0; kt < NT; ++kt) {
    __syncthreads();  // (a) prior compute's LDS reads done
    {
      const float* af = (const float*)ar;
      const float* bf = (const float*)br;
      if constexpr (TM == 16) {
#pragma unroll
        for (int c = 0; c < 16; ++c) As[c][arow] = af[c];
      } else {
#pragma unroll
        for (int c = 0; c < 8; ++c) As[ahalf + c][arow] = af[c];
      }
#pragma unroll
      for (int c = 0; c < 16; ++c) Ws[c][brow] = bf[c];
    }
    __syncthreads();  // (b) staged tile visible
    if (kt + 1 < NT) {  // prefetch next tile; vmcnt wait lands at next (a)+
      const int kb = (kt + 1) * 16;
      if constexpr (TM == 16) {
#pragma unroll
        for (int c = 0; c < 4; ++c) ar[c] = *(const float4*)(Ap + kb + 4 * c);
      } else {
        ar[0] = *(const float4*)(Ap + kb);
        ar[1] = *(const float4*)(Ap + kb + 4);
      }
#pragma unroll
      for (int c = 0; c < 4; ++c) br[c] = *(const float4*)(Wp + kb + 4 * c);
    }
#pragma unroll
    for (int kk = 0; kk < 16; ++kk) {
      float4 aq[TM / 4];
      float4 bq[2];
#pragma unroll
      for (int s = 0; s < TM / 4; ++s)
        aq[s] = *(const float4*)&As[kk][rg * TM + s * 4];
      bq[0] = *(const float4*)&Ws[kk][cg * 8];
      bq[1] = *(const float4*)&Ws[kk][cg * 8 + 4];
      const float* av = (const float*)aq;
      const float* bv = (const float*)bq;
#pragma unroll
      for (int i = 0; i < TM; ++i)
#pragma unroll
        for (int j = 0; j < 8; ++j)
          acc[i][j] = fmaf(av[i], bv[j], acc[i][j]);
    }
  }

  if constexpr (MODE == 0) {
    float4 bb0 = *(const float4*)&bias[n0 + cg * 8];
    float4 bb1 = *(const float4*)&bias[n0 + cg * 8 + 4];
    const float* bv = (const float*)&bb0;  // bb0,bb1 contiguous on stack? no:
    float bvv[8] = {bb0.x, bb0.y, bb0.z, bb0.w, bb1.x, bb1.y, bb1.z, bb1.w};
    (void)bv;
#pragma unroll
    for (int i = 0; i < TM; ++i) {
      float* crow = C + (size_t)(m0 + rg * TM + i) * ldc + n0 + cg * 8;
      float4 o0 = {acc[i][0] + bvv[0], acc[i][1] + bvv[1],
                   acc[i][2] + bvv[2], acc[i][3] + bvv[3]};
      float4 o1 = {acc[i][4] + bvv[4], acc[i][5] + bvv[5],
                   acc[i][6] + bvv[6], acc[i][7] + bvv[7]};
      *(float4*)(crow) = o0;
      *(float4*)(crow + 4) = o1;
    }
  } else {
    // column max over the tile's BM rows -> partial[blockIdx.y][n0+col]
    float cm[8];
#pragma unroll
    for (int j = 0; j < 8; ++j) {
      float m = acc[0][j];
#pragma unroll
      for (int i = 1; i < TM; ++i) m = fmaxf(m, acc[i][j]);
      // reduce over rg within wave (lane bits 4,5)
      m = fmaxf(m, __shfl_xor(m, 16));
      m = fmaxf(m, __shfl_xor(m, 32));
      cm[j] = m;
    }
    const int wv = tid >> 6;
    if ((tid & 63) < 16) {
      float4 c0 = {cm[0], cm[1], cm[2], cm[3]};
      float4 c1 = {cm[4], cm[5], cm[6], cm[7]};
      *(float4*)&red[wv][cg * 8] = c0;
      *(float4*)&red[wv][cg * 8 + 4] = c1;
    }
    __syncthreads();
    if (tid < 128)
      C[(size_t)blockIdx.y * ldc + n0 + tid] =
          fmaxf(red[0][tid], red[1][tid]);
  }
}

// ---------------------------------------------------------------------------
// Flash attention v3, fp32. Block = 128 threads (2 waves); each wave owns a
// 64-row q-tile with 8x8 micro-tiles (1 B/FMA). K/V tiles (64 rows) shared.
// All LDS tiles XOR-swizzled: element (r,c) at col c ^ ((((r>>3)^r)&7)<<3)
// -> every hot read is 2-way (free). P reuses the K buffer for wave0.
// K reg-prefetched one tile ahead; V staged via global_load_lds with
// pre-swizzled per-lane SOURCE (linear LDS dest), drained at the post-QK
// barrier (latency hidden under ~8k cycles of QK). 3 barriers / iter.
// Grid: (S/128, B*H). LDS = 80 KB -> 2 blocks/CU (4 waves = 1/SIMD).
// ---------------------------------------------------------------------------
__device__ __forceinline__ int sx(int r, int c) {
  return c ^ ((((r >> 3) ^ r) & 7) << 3);
}

__global__ __launch_bounds__(128) void attn_kernel(
    const float* __restrict__ qkv, float* __restrict__ ctx) {
  __shared__ float Qs[2][64][64];  // per-wave Q, swizzled (32 KB)
  __shared__ float Ks[64][64];     // shared K tile; becomes wave0's P (16 KB)
  __shared__ float Ps1[64][64];    // wave1's P (16 KB)
  __shared__ float Vs[64][64];     // shared V tile, swizzled (16 KB)
  const int tid = threadIdx.x;
  const int wv = tid >> 6, lane = tid & 63;
  const int rg = lane >> 3, cg = lane & 7;
  const int b = blockIdx.y >> 4, h = blockIdx.y & 15;
  const int q0 = blockIdx.x * 128 + wv * 64;
  const size_t rstride = 3 * Dd;
  const float* qb = qkv + (size_t)b * Ss * rstride + h * HDim;
  const float* kb_ = qb + Dd;
  const float* vb_ = qb + 2 * Dd;

  // stage this wave's Q tile (thread loads row `lane`), swizzled
  {
    const float* qr = qb + (size_t)(q0 + lane) * rstride;
#pragma unroll
    for (int c = 0; c < 64; c += 4)
      *(float4*)&Qs[wv][lane][sx(lane, c)] = *(const float4*)(qr + c);
  }
  // K prefetch regs: thread covers K row tid>>1, half (tid&1)*32
  const int krow = tid >> 1, khalf = (tid & 1) * 32;
  float4 kr[8];
  {
    const float* kp = kb_ + (size_t)krow * rstride + khalf;
#pragma unroll
    for (int c = 0; c < 8; ++c) kr[c] = *(const float4*)(kp + 4 * c);
  }

  float O[8][8] = {};
  float mr[8], lr[8];
#pragma unroll
  for (int i = 0; i < 8; ++i) { mr[i] = -INFINITY; lr[i] = 0.f; }
  float* Pw = (wv == 0) ? &Ks[0][0] : &Ps1[0][0];

#pragma unroll 1
  for (int kt = 0; kt < Ss; kt += 64) {
    __syncthreads();  // (a) prior PV reads of Ks(P)/Vs done; Q staged (it 0)
    // store K regs -> Ks (swizzled); waits on kr loads issued last iter,
    // i.e. after a full compute phase -> hidden
#pragma unroll
    for (int c = 0; c < 8; ++c)
      *(float4*)&Ks[krow][sx(krow, khalf + 4 * c)] = kr[c];
    __syncthreads();  // (b) K tile visible
    // V tile: direct global->LDS, 4 rows per instr; linear LDS dest,
    // swizzle realized by per-lane pre-swizzled global source.
#pragma unroll
    for (int j = 0; j < 8; ++j) {
      const int r0 = wv * 32 + j * 4;
      const int r = r0 + (lane >> 4);
      const int c = ((lane & 15) * 4) ^ ((((r >> 3) ^ r) & 7) << 3);
      const float* src = vb_ + (size_t)(kt + r) * rstride + c;
      float* dst = &Vs[r0][0];
      __builtin_amdgcn_global_load_lds(
          (const __attribute__((address_space(1))) void*)src,
          (__attribute__((address_space(3))) void*)dst, 16, 0, 0);
    }
    // prefetch next K tile (consumed at next iter's stores)
    if (kt + 64 < Ss) {
      const float* kp = kb_ + (size_t)(kt + 64 + krow) * rstride + khalf;
#pragma unroll
      for (int c = 0; c < 8; ++c) kr[c] = *(const float4*)(kp + 4 * c);
    }
    // ---- QK^T: sc[i][j] = sum_d Q[rg*8+i][d] * K[cg*8+j][d]
    float sc[8][8] = {};
#pragma unroll 2
    for (int d0 = 0; d0 < HDim; d0 += 4) {
      float4 qa[8], kv[8];
#pragma unroll
      for (int i = 0; i < 8; ++i) {
        const int r = rg * 8 + i;
        qa[i] = *(const float4*)&Qs[wv][r][sx(r, d0)];
      }
#pragma unroll
      for (int j = 0; j < 8; ++j) {
        const int r = cg * 8 + j;
        kv[j] = *(const float4*)&Ks[r][sx(r, d0)];
      }
#pragma unroll
      for (int i = 0; i < 8; ++i)
#pragma unroll
        for (int j = 0; j < 8; ++j) {
          sc[i][j] = fmaf(qa[i].x, kv[j].x, sc[i][j]);
          sc[i][j] = fmaf(qa[i].y, kv[j].y, sc[i][j]);
          sc[i][j] = fmaf(qa[i].z, kv[j].z, sc[i][j]);
          sc[i][j] = fmaf(qa[i].w, kv[j].w, sc[i][j]);
        }
    }
    __syncthreads();  // (c) all QK reads of Ks done (wave0 overwrites with P);
                      //     V global_load_lds drained (hidden under QK)
    // ---- online softmax (rows r = rg*8+i; k-slice cg*8..+7; 8-lane groups)
#pragma unroll
    for (int i = 0; i < 8; ++i) {
      float sv[8];
#pragma unroll
      for (int j = 0; j < 8; ++j) sv[j] = sc[i][j] * 0.125f;
      float tm = sv[0];
#pragma unroll
      for (int j = 1; j < 8; ++j) tm = fmaxf(tm, sv[j]);
      tm = fmaxf(tm, __shfl_xor(tm, 1));
      tm = fmaxf(tm, __shfl_xor(tm, 2));
      tm = fmaxf(tm, __shfl_xor(tm, 4));
      const float mnew = fmaxf(mr[i], tm);
      float p[8];
      float rs = 0.f;
#pragma unroll
      for (int j = 0; j < 8; ++j) { p[j] = __expf(sv[j] - mnew); rs += p[j]; }
      rs += __shfl_xor(rs, 1);
      rs += __shfl_xor(rs, 2);
      rs += __shfl_xor(rs, 4);
      const float corr = __expf(mr[i] - mnew);
      lr[i] = lr[i] * corr + rs;
      mr[i] = mnew;
#pragma unroll
      for (int c = 0; c < 8; ++c) O[i][c] *= corr;
      const int r = rg * 8 + i;
      float* pp = &Pw[r * 64 + sx(r, cg * 8)];
      float4 p0 = {p[0], p[1], p[2], p[3]};
      float4 p1 = {p[4], p[5], p[6], p[7]};
      *(float4*)pp = p0;
      *(float4*)(pp + 4) = p1;
    }
    // P is wave-private (own rows written/read by same wave); within-wave
    // lgkmcnt ordering suffices -- no extra barrier before PV.
    // ---- PV: O[i][c] += sum_k P[r][k] * V[k][cg*8+c]
#pragma unroll 2
    for (int j0 = 0; j0 < 64; j0 += 4) {
      float4 pa[8];
#pragma unroll
      for (int i = 0; i < 8; ++i) {
        const int r = rg * 8 + i;
        pa[i] = *(const float4*)&Pw[r * 64 + sx(r, j0)];
      }
#pragma unroll
      for (int jj = 0; jj < 4; ++jj) {
        const int vr = j0 + jj;
        const float4 v0 = *(const float4*)&Vs[vr][sx(vr, cg * 8)];
        const float4 v1 = *(const float4*)&Vs[vr][sx(vr, cg * 8) + 4];
#pragma unroll
        for (int i = 0; i < 8; ++i) {
          const float p = (jj == 0) ? pa[i].x
                          : (jj == 1) ? pa[i].y
                          : (jj == 2) ? pa[i].z : pa[i].w;
          O[i][0] = fmaf(p, v0.x, O[i][0]);
          O[i][1] = fmaf(p, v0.y, O[i][1]);
          O[i][2] = fmaf(p, v0.z, O[i][2]);
          O[i][3] = fmaf(p, v0.w, O[i][3]);
          O[i][4] = fmaf(p, v1.x, O[i][4]);
          O[i][5] = fmaf(p, v1.y, O[i][5]);
          O[i][6] = fmaf(p, v1.z, O[i][6]);
          O[i][7] = fmaf(p, v1.w, O[i][7]);
        }
      }
    }
  }
  // epilogue: normalize and store
#pragma unroll
  for (int i = 0; i < 8; ++i) {
    const float inv = 1.0f / lr[i];
    float* orow =
        ctx + ((size_t)(b * Ss + q0 + rg * 8 + i)) * Dd + h * HDim + cg * 8;
    float4 o0 = {O[i][0] * inv, O[i][1] * inv, O[i][2] * inv, O[i][3] * inv};
    float4 o1 = {O[i][4] * inv, O[i][5] * inv, O[i][6] * inv, O[i][7] * inv};
    *(float4*)(orow) = o0;
    *(float4*)(orow + 4) = o1;
  }
}

// ---------------------------------------------------------------------------
// Router: bitonic full-sort of packed u64 keys (exact stable top-k).
// key = sortable(value)<<32 | (Nn-1-n): descending u64 order == descending
// value with ascending-index tiebreak == jax.lax.top_k order, exactly.
// ---------------------------------------------------------------------------
__device__ inline unsigned int f2s(float f) {
  unsigned int u = __float_as_uint(f);
  return (u >> 31) ? ~u : (u | 0x80000000u);
}
__device__ inline float s2f(unsigned int s) {
  unsigned int u = (s >> 31) ? (s & 0x7fffffffu) : ~s;
  return __uint_as_float(u);
}

__global__ __launch_bounds__(256) void router_kernel(
    const float* __restrict__ partial, const float* __restrict__ aff_b,
    const int* __restrict__ kp, float* __restrict__ out, int out_size) {
  __shared__ unsigned long long keys[Nn];  // 32 KB
  __shared__ float lorig[Nn];              // 16 KB
  __shared__ float rv[4];
  const int tid = threadIdx.x;
  const int b = blockIdx.x;
  const int kcount = *kp;
  float* idx_out = out;
  float* w_out = out + (out_size - Mm * Dd - Bb * Nn);
  for (int n = tid; n < Nn; n += 256) {
    float m = partial[(size_t)(b * 8) * Nn + n];
#pragma unroll
    for (int t = 1; t < 8; ++t)
      m = fmaxf(m, partial[(size_t)(b * 8 + t) * Nn + n]);
    float lg = (m + aff_b[n]) * 0.5f;  // /TEMPERATURE
    lorig[n] = lg;
    keys[n] = ((unsigned long long)f2s(lg) << 32) | (unsigned int)(Nn - 1 - n);
  }
  __syncthreads();
  for (int kk = 2; kk <= Nn; kk <<= 1) {
    for (int j = kk >> 1; j > 0; j >>= 1) {
#pragma unroll 4
      for (int t = tid; t < Nn / 2; t += 256) {
        const int i = 2 * j * (t / j) + (t % j);
        const int p = i + j;
        const bool desc = ((i & kk) == 0);
        unsigned long long a = keys[i], c = keys[p];
        if (desc ? (a < c) : (a > c)) { keys[i] = c; keys[p] = a; }
      }
      __syncthreads();
    }
  }
  const float gm = s2f((unsigned int)(keys[0] >> 32));
  float se = 0.f;
  for (int n = tid; n < Nn; n += 256) se += expf(lorig[n] - gm);
#pragma unroll
  for (int msk = 1; msk < 64; msk <<= 1) se += __shfl_xor(se, msk);
  if ((tid & 63) == 0) rv[tid >> 6] = se;
  __syncthreads();
  se = rv[0] + rv[1] + rv[2] + rv[3];
  __syncthreads();
  float es = 0.f;
  for (int p = tid; p < kcount; p += 256)
    es += expf(s2f((unsigned int)(keys[p] >> 32)) - gm);
#pragma unroll
  for (int msk = 1; msk < 64; msk <<= 1) es += __shfl_xor(es, msk);
  if ((tid & 63) == 0) rv[tid >> 6] = es;
  __syncthreads();
  es = rv[0] + rv[1] + rv[2] + rv[3];
  const float wd = es / se + 1e-8f;
  for (int n = tid; n < Nn; n += 256) w_out[(size_t)b * Nn + n] = 0.f;
  __syncthreads();
  for (int p = tid; p < kcount; p += 256) {
    const unsigned long long kkey = keys[p];
    const int n = Nn - 1 - (int)(kkey & 0xffffffffu);
    const float val = s2f((unsigned int)(kkey >> 32));
    idx_out[b * kcount + p] = (float)n;
    w_out[(size_t)b * Nn + n] = (expf(val - gm) / se) / wd;
  }
}

}  // namespace

extern "C" void kernel_launch(void* const* d_in, const int* in_sizes, int n_in,
                              void* d_out, int out_size, void* d_ws,
                              size_t ws_size, hipStream_t stream) {
  (void)in_sizes; (void)n_in; (void)ws_size;
  const float* x = (const float*)d_in[0];
  const float* in_proj_w = (const float*)d_in[1];
  const float* in_proj_b = (const float*)d_in[2];
  const float* out_w = (const float*)d_in[3];
  const float* out_b = (const float*)d_in[4];
  const float* aff_w = (const float*)d_in[5];
  const float* aff_b = (const float*)d_in[6];
  const int* kp = (const int*)d_in[7];

  float* qkv = (float*)d_ws;                 // [4096, 3072] = 50.3 MB
  float* ctxws = qkv + (size_t)Mm * 3 * Dd;  // [4096, 1024] = 16.8 MB
  float* partial = ctxws + (size_t)Mm * Dd;  // [32, 4096]   = 0.5 MB

  float* out = (float*)d_out;
  float* ctx_out = out + ((size_t)out_size - (size_t)Mm * Dd);  // context tail

  // 1) qkv = x @ in_proj_w^T + b   (TM=16, grid 24x32 = 768 blocks)
  gemm_f32<0, 16><<<dim3(3 * Dd / 128, Mm / 128), 128, 0, stream>>>(
      x, in_proj_w, in_proj_b, qkv, Dd, 3 * Dd);
  // 2) attention -> ctxws (merged heads)  (grid 8x64 = 512 blocks)
  attn_kernel<<<dim3(Ss / 128, Bb * Hh), 128, 0, stream>>>(qkv, ctxws);
  // 3) context = ctxws @ out_w^T + b  (TM=8 -> BM=64, grid 8x64 = 512 blocks)
  gemm_f32<0, 8><<<dim3(Dd / 128, Mm / 64), 128, 0, stream>>>(
      ctxws, out_w, out_b, ctx_out, Dd, Dd);
  // 4) partial[mtile][n] = max over 128 rows of (context @ aff_w^T)
  gemm_f32<2, 16><<<dim3(Nn / 128, Mm / 128), 128, 0, stream>>>(
      ctx_out, aff_w, nullptr, partial, Dd, Nn);
  // 5) router: pooled max, softmax, exact top-k, weights
  router_kernel<<<dim3(Bb), 256, 0, stream>>>(partial, aff_b, kp, out, out_size);
}

// Round 6
// 1559.918 us; speedup vs baseline: 1.8319x; 1.8319x over previous
//
#include <hip/hip_runtime.h>
#include <math.h>

namespace {

constexpr int Bb = 4, Ss = 1024, Dd = 1024, Hh = 16, HDim = 64, Nn = 4096;
constexpr int Mm = Bb * Ss; // 4096

// ---------------------------------------------------------------------------
// fp32 GEMM v4: C[M,N] = A[M,K] @ W[N,K]^T (+ bias[N]).
// 256 threads = 4 waves (2x2 quadrants of 64x64), 8x8 micro-tile (64 acc
// VGPRs; total ~115 -> no spill at the __launch_bounds__(256,4) cap of 128).
// SINGLE LDS buffer + TWO barriers per K-tile; the global prefetch for tile
// kt+1 is issued after barrier (b), so the compiler's mandatory vmcnt(0)
// drain lands at the *next* barrier (a) -- after the full 16x64-FMA compute
// phase -> HBM latency fully hidden (fixes r4's exposed-at-barrier stall).
// LDS access: A-reads 8-way broadcast + 2-way bank alias (free); B-reads
// 8-way broadcast + 2-way alias (free); staging writes 2-way (free).
// MODE 0: C = acc + bias.  MODE 2: partial[blockIdx.y][n] = max over the
// tile's 128 rows (feeds the router's pooled max).
// ---------------------------------------------------------------------------
template <int MODE>
__global__ __launch_bounds__(256, 4) void gemm_f32(
    const float* __restrict__ A, const float* __restrict__ W,
    const float* __restrict__ bias, float* __restrict__ C, const int K,
    const int ldc) {
  __shared__ float As[16][128];
  __shared__ float Ws[16][128];
  __shared__ float red[2][128];  // MODE2 cross-wave reduction
  const int tid = threadIdx.x;
  const int lane = tid & 63, wv = tid >> 6;
  const int wm = wv >> 1, wn = wv & 1;
  const int lty = lane >> 3, ltx = lane & 7;
  const int m0 = blockIdx.y * 128, n0 = blockIdx.x * 128;
  const int row0 = wm * 64 + lty * 8;
  const int col0 = wn * 64 + ltx * 8;
  const int srow = tid >> 1, shalf = (tid & 1) * 8;  // staging row / k-half
  const float* Ap = A + (size_t)(m0 + srow) * K + shalf;
  const float* Wp = W + (size_t)(n0 + srow) * K + shalf;

  // preload tile 0
  float4 ar0 = *(const float4*)(Ap), ar1 = *(const float4*)(Ap + 4);
  float4 wr0 = *(const float4*)(Wp), wr1 = *(const float4*)(Wp + 4);

  float acc[8][8] = {};
  const int NT = K / 16;
#pragma unroll 1
  for (int kt = 0; kt < NT; ++kt) {
    __syncthreads();  // (a) prior compute's LDS reads done
    As[shalf + 0][srow] = ar0.x; As[shalf + 1][srow] = ar0.y;
    As[shalf + 2][srow] = ar0.z; As[shalf + 3][srow] = ar0.w;
    As[shalf + 4][srow] = ar1.x; As[shalf + 5][srow] = ar1.y;
    As[shalf + 6][srow] = ar1.z; As[shalf + 7][srow] = ar1.w;
    Ws[shalf + 0][srow] = wr0.x; Ws[shalf + 1][srow] = wr0.y;
    Ws[shalf + 2][srow] = wr0.z; Ws[shalf + 3][srow] = wr0.w;
    Ws[shalf + 4][srow] = wr1.x; Ws[shalf + 5][srow] = wr1.y;
    Ws[shalf + 6][srow] = wr1.z; Ws[shalf + 7][srow] = wr1.w;
    __syncthreads();  // (b) staged tile visible
    if (kt + 1 < NT) {  // prefetch next tile; drained at next (a) -> hidden
      const int kb = (kt + 1) * 16;
      ar0 = *(const float4*)(Ap + kb);
      ar1 = *(const float4*)(Ap + kb + 4);
      wr0 = *(const float4*)(Wp + kb);
      wr1 = *(const float4*)(Wp + kb + 4);
    }
#pragma unroll
    for (int kk = 0; kk < 16; ++kk) {
      float4 a0 = *(const float4*)&As[kk][row0];
      float4 a1 = *(const float4*)&As[kk][row0 + 4];
      float4 b0 = *(const float4*)&Ws[kk][col0];
      float4 b1 = *(const float4*)&Ws[kk][col0 + 4];
      float av[8] = {a0.x, a0.y, a0.z, a0.w, a1.x, a1.y, a1.z, a1.w};
      float bv[8] = {b0.x, b0.y, b0.z, b0.w, b1.x, b1.y, b1.z, b1.w};
#pragma unroll
      for (int i = 0; i < 8; ++i)
#pragma unroll
        for (int j = 0; j < 8; ++j)
          acc[i][j] = fmaf(av[i], bv[j], acc[i][j]);
    }
  }

  if constexpr (MODE == 0) {
    float4 bb0 = *(const float4*)&bias[n0 + col0];
    float4 bb1 = *(const float4*)&bias[n0 + col0 + 4];
    const float bvv[8] = {bb0.x, bb0.y, bb0.z, bb0.w,
                          bb1.x, bb1.y, bb1.z, bb1.w};
#pragma unroll
    for (int i = 0; i < 8; ++i) {
      float* crow = C + (size_t)(m0 + row0 + i) * ldc + n0 + col0;
      float4 o0 = {acc[i][0] + bvv[0], acc[i][1] + bvv[1],
                   acc[i][2] + bvv[2], acc[i][3] + bvv[3]};
      float4 o1 = {acc[i][4] + bvv[4], acc[i][5] + bvv[5],
                   acc[i][6] + bvv[6], acc[i][7] + bvv[7]};
      *(float4*)(crow) = o0;
      *(float4*)(crow + 4) = o1;
    }
  } else {
    // column max over the tile's 128 rows -> partial[blockIdx.y][n0+col]
    float cm[8];
#pragma unroll
    for (int j = 0; j < 8; ++j) {
      float m = acc[0][j];
#pragma unroll
      for (int i = 1; i < 8; ++i) m = fmaxf(m, acc[i][j]);
      m = fmaxf(m, __shfl_xor(m, 8));   // reduce over lty (lane bits 3..5)
      m = fmaxf(m, __shfl_xor(m, 16));
      m = fmaxf(m, __shfl_xor(m, 32));
      cm[j] = m;
    }
    __syncthreads();  // all K-loop LDS reads done
    if (lty == 0) {
      float4 c0 = {cm[0], cm[1], cm[2], cm[3]};
      float4 c1 = {cm[4], cm[5], cm[6], cm[7]};
      *(float4*)&red[wm][wn * 64 + ltx * 8] = c0;
      *(float4*)&red[wm][wn * 64 + ltx * 8 + 4] = c1;
    }
    __syncthreads();
    if (tid < 128)
      C[(size_t)blockIdx.y * ldc + n0 + tid] =
          fmaxf(red[0][tid], red[1][tid]);
  }
}

// ---------------------------------------------------------------------------
// Flash attention v3 (validated in r5), fp32. Block = 128 threads (2 waves);
// each wave owns a 64-row q-tile with 8x8 micro-tiles (1 B/FMA). K/V tiles
// shared. All LDS tiles XOR-swizzled -> hot reads 2-way (free). P reuses the
// K buffer for wave0. K reg-prefetched one tile ahead (drained at barrier c,
// after QK compute -> hidden); V staged via global_load_lds with pre-swizzled
// per-lane source (linear LDS dest), drained at barrier (c) too.
// Grid: (S/128, B*H). LDS = 80 KB -> 2 blocks/CU.
// ---------------------------------------------------------------------------
__device__ __forceinline__ int sx(int r, int c) {
  return c ^ ((((r >> 3) ^ r) & 7) << 3);
}

__global__ __launch_bounds__(128) void attn_kernel(
    const float* __restrict__ qkv, float* __restrict__ ctx) {
  __shared__ float Qs[2][64][64];  // per-wave Q, swizzled (32 KB)
  __shared__ float Ks[64][64];     // shared K tile; becomes wave0's P (16 KB)
  __shared__ float Ps1[64][64];    // wave1's P (16 KB)
  __shared__ float Vs[64][64];     // shared V tile, swizzled (16 KB)
  const int tid = threadIdx.x;
  const int wv = tid >> 6, lane = tid & 63;
  const int rg = lane >> 3, cg = lane & 7;
  const int b = blockIdx.y >> 4, h = blockIdx.y & 15;
  const int q0 = blockIdx.x * 128 + wv * 64;
  const size_t rstride = 3 * Dd;
  const float* qb = qkv + (size_t)b * Ss * rstride + h * HDim;
  const float* kb_ = qb + Dd;
  const float* vb_ = qb + 2 * Dd;

  {
    const float* qr = qb + (size_t)(q0 + lane) * rstride;
#pragma unroll
    for (int c = 0; c < 64; c += 4)
      *(float4*)&Qs[wv][lane][sx(lane, c)] = *(const float4*)(qr + c);
  }
  const int krow = tid >> 1, khalf = (tid & 1) * 32;
  float4 kr[8];
  {
    const float* kp = kb_ + (size_t)krow * rstride + khalf;
#pragma unroll
    for (int c = 0; c < 8; ++c) kr[c] = *(const float4*)(kp + 4 * c);
  }

  float O[8][8] = {};
  float mr[8], lr[8];
#pragma unroll
  for (int i = 0; i < 8; ++i) { mr[i] = -INFINITY; lr[i] = 0.f; }
  float* Pw = (wv == 0) ? &Ks[0][0] : &Ps1[0][0];

#pragma unroll 1
  for (int kt = 0; kt < Ss; kt += 64) {
    __syncthreads();  // (a) prior PV reads of Ks(P)/Vs done; Q staged (it 0)
#pragma unroll
    for (int c = 0; c < 8; ++c)
      *(float4*)&Ks[krow][sx(krow, khalf + 4 * c)] = kr[c];
    __syncthreads();  // (b) K tile visible
#pragma unroll
    for (int j = 0; j < 8; ++j) {
      const int r0 = wv * 32 + j * 4;
      const int r = r0 + (lane >> 4);
      const int c = ((lane & 15) * 4) ^ ((((r >> 3) ^ r) & 7) << 3);
      const float* src = vb_ + (size_t)(kt + r) * rstride + c;
      float* dst = &Vs[r0][0];
      __builtin_amdgcn_global_load_lds(
          (const __attribute__((address_space(1))) void*)src,
          (__attribute__((address_space(3))) void*)dst, 16, 0, 0);
    }
    if (kt + 64 < Ss) {  // prefetch next K tile (drained at (c) -> hidden)
      const float* kp = kb_ + (size_t)(kt + 64 + krow) * rstride + khalf;
#pragma unroll
      for (int c = 0; c < 8; ++c) kr[c] = *(const float4*)(kp + 4 * c);
    }
    // ---- QK^T
    float sc[8][8] = {};
#pragma unroll 2
    for (int d0 = 0; d0 < HDim; d0 += 4) {
      float4 qa[8], kv[8];
#pragma unroll
      for (int i = 0; i < 8; ++i) {
        const int r = rg * 8 + i;
        qa[i] = *(const float4*)&Qs[wv][r][sx(r, d0)];
      }
#pragma unroll
      for (int j = 0; j < 8; ++j) {
        const int r = cg * 8 + j;
        kv[j] = *(const float4*)&Ks[r][sx(r, d0)];
      }
#pragma unroll
      for (int i = 0; i < 8; ++i)
#pragma unroll
        for (int j = 0; j < 8; ++j) {
          sc[i][j] = fmaf(qa[i].x, kv[j].x, sc[i][j]);
          sc[i][j] = fmaf(qa[i].y, kv[j].y, sc[i][j]);
          sc[i][j] = fmaf(qa[i].z, kv[j].z, sc[i][j]);
          sc[i][j] = fmaf(qa[i].w, kv[j].w, sc[i][j]);
        }
    }
    __syncthreads();  // (c) QK reads done; V drained; K prefetch drained
    // ---- online softmax
#pragma unroll
    for (int i = 0; i < 8; ++i) {
      float sv[8];
#pragma unroll
      for (int j = 0; j < 8; ++j) sv[j] = sc[i][j] * 0.125f;
      float tm = sv[0];
#pragma unroll
      for (int j = 1; j < 8; ++j) tm = fmaxf(tm, sv[j]);
      tm = fmaxf(tm, __shfl_xor(tm, 1));
      tm = fmaxf(tm, __shfl_xor(tm, 2));
      tm = fmaxf(tm, __shfl_xor(tm, 4));
      const float mnew = fmaxf(mr[i], tm);
      float p[8];
      float rs = 0.f;
#pragma unroll
      for (int j = 0; j < 8; ++j) { p[j] = __expf(sv[j] - mnew); rs += p[j]; }
      rs += __shfl_xor(rs, 1);
      rs += __shfl_xor(rs, 2);
      rs += __shfl_xor(rs, 4);
      const float corr = __expf(mr[i] - mnew);
      lr[i] = lr[i] * corr + rs;
      mr[i] = mnew;
#pragma unroll
      for (int c = 0; c < 8; ++c) O[i][c] *= corr;
      const int r = rg * 8 + i;
      float* pp = &Pw[r * 64 + sx(r, cg * 8)];
      float4 p0 = {p[0], p[1], p[2], p[3]};
      float4 p1 = {p[4], p[5], p[6], p[7]};
      *(float4*)pp = p0;
      *(float4*)(pp + 4) = p1;
    }
    // P wave-private; within-wave lgkmcnt ordering suffices
    // ---- PV
#pragma unroll 2
    for (int j0 = 0; j0 < 64; j0 += 4) {
      float4 pa[8];
#pragma unroll
      for (int i = 0; i < 8; ++i) {
        const int r = rg * 8 + i;
        pa[i] = *(const float4*)&Pw[r * 64 + sx(r, j0)];
      }
#pragma unroll
      for (int jj = 0; jj < 4; ++jj) {
        const int vr = j0 + jj;
        const float4 v0 = *(const float4*)&Vs[vr][sx(vr, cg * 8)];
        const float4 v1 = *(const float4*)&Vs[vr][sx(vr, cg * 8) + 4];
#pragma unroll
        for (int i = 0; i < 8; ++i) {
          const float p = (jj == 0) ? pa[i].x
                          : (jj == 1) ? pa[i].y
                          : (jj == 2) ? pa[i].z : pa[i].w;
          O[i][0] = fmaf(p, v0.x, O[i][0]);
          O[i][1] = fmaf(p, v0.y, O[i][1]);
          O[i][2] = fmaf(p, v0.z, O[i][2]);
          O[i][3] = fmaf(p, v0.w, O[i][3]);
          O[i][4] = fmaf(p, v1.x, O[i][4]);
          O[i][5] = fmaf(p, v1.y, O[i][5]);
          O[i][6] = fmaf(p, v1.z, O[i][6]);
          O[i][7] = fmaf(p, v1.w, O[i][7]);
        }
      }
    }
  }
#pragma unroll
  for (int i = 0; i < 8; ++i) {
    const float inv = 1.0f / lr[i];
    float* orow =
        ctx + ((size_t)(b * Ss + q0 + rg * 8 + i)) * Dd + h * HDim + cg * 8;
    float4 o0 = {O[i][0] * inv, O[i][1] * inv, O[i][2] * inv, O[i][3] * inv};
    float4 o1 = {O[i][4] * inv, O[i][5] * inv, O[i][6] * inv, O[i][7] * inv};
    *(float4*)(orow) = o0;
    *(float4*)(orow + 4) = o1;
  }
}

// ---------------------------------------------------------------------------
// Router: bitonic full-sort of packed u64 keys (exact stable top-k).
// ---------------------------------------------------------------------------
__device__ inline unsigned int f2s(float f) {
  unsigned int u = __float_as_uint(f);
  return (u >> 31) ? ~u : (u | 0x80000000u);
}
__device__ inline float s2f(unsigned int s) {
  unsigned int u = (s >> 31) ? (s & 0x7fffffffu) : ~s;
  return __uint_as_float(u);
}

__global__ __launch_bounds__(256) void router_kernel(
    const float* __restrict__ partial, const float* __restrict__ aff_b,
    const int* __restrict__ kp, float* __restrict__ out, int out_size) {
  __shared__ unsigned long long keys[Nn];  // 32 KB
  __shared__ float lorig[Nn];              // 16 KB
  __shared__ float rv[4];
  const int tid = threadIdx.x;
  const int b = blockIdx.x;
  const int kcount = *kp;
  float* idx_out = out;
  float* w_out = out + (out_size - Mm * Dd - Bb * Nn);
  for (int n = tid; n < Nn; n += 256) {
    float m = partial[(size_t)(b * 8) * Nn + n];
#pragma unroll
    for (int t = 1; t < 8; ++t)
      m = fmaxf(m, partial[(size_t)(b * 8 + t) * Nn + n]);
    float lg = (m + aff_b[n]) * 0.5f;  // /TEMPERATURE
    lorig[n] = lg;
    keys[n] = ((unsigned long long)f2s(lg) << 32) | (unsigned int)(Nn - 1 - n);
  }
  __syncthreads();
  for (int kk = 2; kk <= Nn; kk <<= 1) {
    for (int j = kk >> 1; j > 0; j >>= 1) {
#pragma unroll 4
      for (int t = tid; t < Nn / 2; t += 256) {
        const int i = 2 * j * (t / j) + (t % j);
        const int p = i + j;
        const bool desc = ((i & kk) == 0);
        unsigned long long a = keys[i], c = keys[p];
        if (desc ? (a < c) : (a > c)) { keys[i] = c; keys[p] = a; }
      }
      __syncthreads();
    }
  }
  const float gm = s2f((unsigned int)(keys[0] >> 32));
  float se = 0.f;
  for (int n = tid; n < Nn; n += 256) se += expf(lorig[n] - gm);
#pragma unroll
  for (int msk = 1; msk < 64; msk <<= 1) se += __shfl_xor(se, msk);
  if ((tid & 63) == 0) rv[tid >> 6] = se;
  __syncthreads();
  se = rv[0] + rv[1] + rv[2] + rv[3];
  __syncthreads();
  float es = 0.f;
  for (int p = tid; p < kcount; p += 256)
    es += expf(s2f((unsigned int)(keys[p] >> 32)) - gm);
#pragma unroll
  for (int msk = 1; msk < 64; msk <<= 1) es += __shfl_xor(es, msk);
  if ((tid & 63) == 0) rv[tid >> 6] = es;
  __syncthreads();
  es = rv[0] + rv[1] + rv[2] + rv[3];
  const float wd = es / se + 1e-8f;
  for (int n = tid; n < Nn; n += 256) w_out[(size_t)b * Nn + n] = 0.f;
  __syncthreads();
  for (int p = tid; p < kcount; p += 256) {
    const unsigned long long kkey = keys[p];
    const int n = Nn - 1 - (int)(kkey & 0xffffffffu);
    const float val = s2f((unsigned int)(kkey >> 32));
    idx_out[b * kcount + p] = (float)n;
    w_out[(size_t)b * Nn + n] = (expf(val - gm) / se) / wd;
  }
}

}  // namespace

extern "C" void kernel_launch(void* const* d_in, const int* in_sizes, int n_in,
                              void* d_out, int out_size, void* d_ws,
                              size_t ws_size, hipStream_t stream) {
  (void)in_sizes; (void)n_in; (void)ws_size;
  const float* x = (const float*)d_in[0];
  const float* in_proj_w = (const float*)d_in[1];
  const float* in_proj_b = (const float*)d_in[2];
  const float* out_w = (const float*)d_in[3];
  const float* out_b = (const float*)d_in[4];
  const float* aff_w = (const float*)d_in[5];
  const float* aff_b = (const float*)d_in[6];
  const int* kp = (const int*)d_in[7];

  float* qkv = (float*)d_ws;                 // [4096, 3072] = 50.3 MB
  float* ctxws = qkv + (size_t)Mm * 3 * Dd;  // [4096, 1024] = 16.8 MB
  float* partial = ctxws + (size_t)Mm * Dd;  // [32, 4096]   = 0.5 MB

  float* out = (float*)d_out;
  float* ctx_out = out + ((size_t)out_size - (size_t)Mm * Dd);  // context tail

  // 1) qkv = x @ in_proj_w^T + b   (grid 24x32 = 768 blocks)
  gemm_f32<0><<<dim3(3 * Dd / 128, Mm / 128), 256, 0, stream>>>(
      x, in_proj_w, in_proj_b, qkv, Dd, 3 * Dd);
  // 2) attention -> ctxws (merged heads)  (grid 8x64 = 512 blocks)
  attn_kernel<<<dim3(Ss / 128, Bb * Hh), 128, 0, stream>>>(qkv, ctxws);
  // 3) context = ctxws @ out_w^T + b  (grid 8x32 = 256 blocks)
  gemm_f32<0><<<dim3(Dd / 128, Mm / 128), 256, 0, stream>>>(
      ctxws, out_w, out_b, ctx_out, Dd, Dd);
  // 4) partial[mtile][n] = max over 128 rows of (context @ aff_w^T)
  gemm_f32<2><<<dim3(Nn / 128, Mm / 128), 256, 0, stream>>>(
      ctx_out, aff_w, nullptr, partial, Dd, Nn);
  // 5) router: pooled max, softmax, exact top-k, weights
  router_kernel<<<dim3(Bb), 256, 0, stream>>>(partial, aff_b, kp, out, out_size);
}